// Round 7
// baseline (163.657 us; speedup 1.0000x reference)
//
#include <hip/hip_runtime.h>

// NavierStokesLoss: fused jet-propagation (8 channels/point) through
// 4->256->256->5 tanh MLP, bf16 MFMA, f32 elsewhere.
// R7: statically anti-phased wave groups. 256 persistent blocks, 8 waves =
// 2 groups x 4 waves. Group g processes tiles 2j+g (8 pts each) in its own
// 2-buffer LDS region. Group schedules are shifted one barrier interval, so
// in every interval one group issues MFMA (GEMM3(j-1), GEMM2(j)) while the
// other issues VALU (RC(j), L1(j+1)) -> MFMA/VALU pipes co-issue per SIMD.
// Wave tile 64x64xK256 (acc[4][4]) removes B duplication: 128KB VMEM/tile.

#define NPTS 65536
#define TPB  8                 // points per tile
#define NBLOCKS 256
#define TILES 32               // tiles per block (16 per group)
#define KPAD 264
#define W3T_OFF 135168         // 256*264*2
#define PART_OFF 143360
#define TSZ 32768              // bytes per 64-row jet tile

typedef short s16x8 __attribute__((ext_vector_type(8)));
typedef float f32x4 __attribute__((ext_vector_type(4)));

static __device__ __forceinline__ unsigned short f2bf(float f){
  unsigned int u = __float_as_uint(f);
  u = (u + 0x7FFFu + ((u >> 16) & 1u)) >> 16;   // RNE
  return (unsigned short)u;
}
static __device__ __forceinline__ unsigned cvtpk_bf16(float lo, float hi){
  unsigned r;
  asm("v_cvt_pk_bf16_f32 %0, %1, %2" : "=v"(r) : "v"(lo), "v"(hi));
  return r;
}
static __device__ __forceinline__ float fast_tanh(float x){
  float e = __builtin_amdgcn_exp2f(x * 2.8853900817779268f);   // exp(2x)
  return 1.f - 2.f * __builtin_amdgcn_rcpf(e + 1.f);
}

__global__ void prep_w2t(const float* __restrict__ W2, unsigned short* __restrict__ w2t){
  int k = blockIdx.x, j = threadIdx.x;
  w2t[j * KPAD + k] = f2bf(W2[k * 256 + j]);
}
__global__ void prep_w3t(const float* __restrict__ W3, unsigned short* __restrict__ w3t){
  int idx = blockIdx.x * 256 + threadIdx.x;
  int n = idx >> 8, k = idx & 255;
  w3t[n * 256 + k] = (n < 5) ? f2bf(W3[k * 5 + n]) : (unsigned short)0;
}

// Jet-tile row layout (64 rows x 256 bf16, 512B XOR-swizzled rows):
//   row(p,c) = (p&4)*8 + (c&4)*4 + (p&3)*4 + (c&3)
__launch_bounds__(512, 2)
__global__ void ns_main(const float* __restrict__ pts, const float* __restrict__ times,
                        const float* __restrict__ visc,
                        const float* __restrict__ W1, const float* __restrict__ b1,
                        const float* __restrict__ b2, const float* __restrict__ b3,
                        const unsigned short* __restrict__ w2t,
                        const unsigned short* __restrict__ w3t,
                        float* __restrict__ parts){
  __shared__ __align__(16) unsigned char sA[4 * TSZ];   // 128 KiB: grp*2 + (j&1)

  const int t   = threadIdx.x;
  const int blk = blockIdx.x;
  const int wid = t >> 6, lane = t & 63;
  const int grp = wid >> 2, q = wid & 3;      // group, wave-in-group
  const int g = lane >> 4, r16 = lane & 15;
  const int xorv = (r16 & 7) << 4;
  const int jo = lane << 2;                   // 4 consecutive j per lane (L1)

  // ---------------- persistent state ----------------
  const float4 wa  = *(const float4*)(W1 + jo);
  const float4 wb  = *(const float4*)(W1 + 256 + jo);
  const float4 wc4 = *(const float4*)(W1 + 512 + jo);
  const float4 wd  = *(const float4*)(W1 + 768 + jo);
  const float4 bb  = *(const float4*)(b1 + jo);

  const unsigned char* w2tB = (const unsigned char*)w2t;
  const unsigned char* bp0 = w2tB + (((q*64 +  0 + r16)*KPAD + g*8) << 1);
  const unsigned char* bp1 = w2tB + (((q*64 + 16 + r16)*KPAD + g*8) << 1);
  const unsigned char* bp2 = w2tB + (((q*64 + 32 + r16)*KPAD + g*8) << 1);
  const unsigned char* bp3 = w2tB + (((q*64 + 48 + r16)*KPAD + g*8) << 1);
  float b2c[4];
  #pragma unroll
  for (int nt = 0; nt < 4; ++nt) b2c[nt] = b2[q*64 + nt*16 + r16];
  const unsigned char* w3tB = (const unsigned char*)w3t + ((r16*256 + g*8) << 1);
  const float b3v = (r16 < 5) ? b3[r16] : 0.f;

  // GEMM3 row addressing: wave q owns points 2q, 2q+1 of its tile
  const int ptL  = 2*q + ((r16 >> 2) & 1);
  const int jrow = ((ptL & 4) << 3) + ((ptL & 3) << 2) + (r16 & 3) + ((r16 >> 3) << 4);
  const int g3off = jrow * 512;
  const int g3sw  = (jrow & 7) << 4;

  const int tbase = blk * (TILES * TPB);      // 256 points per block

  float accM = 0.f, accC = 0.f;
  f32x4 acc[4][4];

  // layer-1 for 2 points (2q, 2q+1 of tile) into BASE
#define L1_T(NBASE, BASE) do {                                                  \
    _Pragma("unroll")                                                           \
    for (int pp = 0; pp < 2; ++pp){                                             \
      int p_ = 2*q + pp;                                                        \
      int n_ = (NBASE) + p_;                                                    \
      float z0_ = pts[n_*3+0], z1_ = pts[n_*3+1], z2_ = pts[n_*3+2], z3_ = times[n_]; \
      float th_[4], sg_[4], m2_[4];                                             \
      _Pragma("unroll")                                                         \
      for (int jj = 0; jj < 4; ++jj){                                           \
        float a_ = (&bb.x)[jj] + z0_*(&wa.x)[jj] + z1_*(&wb.x)[jj]              \
                               + z2_*(&wc4.x)[jj] + z3_*(&wd.x)[jj];            \
        float h_ = fast_tanh(a_);                                               \
        th_[jj] = h_; sg_[jj] = 1.f - h_*h_; m2_[jj] = -2.f*h_*sg_[jj];         \
      }                                                                         \
      _Pragma("unroll")                                                         \
      for (int c = 0; c < 8; ++c){                                              \
        float x_[4];                                                            \
        _Pragma("unroll")                                                       \
        for (int jj = 0; jj < 4; ++jj){                                         \
          float w0_ = (&wa.x)[jj], w1_ = (&wb.x)[jj], w2_ = (&wc4.x)[jj];       \
          float v_;                                                             \
          if      (c == 0) v_ = th_[jj];                                        \
          else if (c == 1) v_ = sg_[jj]*w0_;                                    \
          else if (c == 2) v_ = sg_[jj]*w1_;                                    \
          else if (c == 3) v_ = sg_[jj]*w2_;                                    \
          else if (c == 4) v_ = sg_[jj]*(&wd.x)[jj];                            \
          else if (c == 5) v_ = m2_[jj]*w0_*w0_;                                \
          else if (c == 6) v_ = m2_[jj]*w1_*w1_;                                \
          else             v_ = m2_[jj]*w2_*w2_;                                \
          x_[jj] = v_;                                                          \
        }                                                                       \
        int row_ = ((p_ & 4) << 3) + ((c & 4) << 2) + ((p_ & 3) << 2) + (c & 3);\
        int off_ = row_*512 + ((jo << 1) ^ ((row_ & 7) << 4));                  \
        uint2 v2_; v2_.x = cvtpk_bf16(x_[0], x_[1]); v2_.y = cvtpk_bf16(x_[2], x_[3]); \
        *(uint2*)((BASE) + off_) = v2_;                                         \
      }                                                                         \
    }                                                                           \
  } while (0)

  // GEMM2: full 64 rows x cols q*64..q*64+63 x K=256, acc[4][4]
#define G2_T(BASE) do {                                                         \
    _Pragma("unroll")                                                           \
    for (int a_ = 0; a_ < 4; ++a_)                                              \
      _Pragma("unroll")                                                         \
      for (int b_ = 0; b_ < 4; ++b_)                                            \
        acc[a_][b_] = (f32x4){0.f, 0.f, 0.f, 0.f};                              \
    int abase_ = r16*512;                                                       \
    _Pragma("unroll")                                                           \
    for (int ks = 0; ks < 8; ++ks){                                             \
      int X_ = ((ks*64) + (g << 4)) ^ xorv;                                     \
      s16x8 af0_ = *(const s16x8*)((BASE) + abase_ + X_);                       \
      s16x8 af1_ = *(const s16x8*)((BASE) + abase_ +  8192 + X_);               \
      s16x8 af2_ = *(const s16x8*)((BASE) + abase_ + 16384 + X_);               \
      s16x8 af3_ = *(const s16x8*)((BASE) + abase_ + 24576 + X_);               \
      s16x8 b0_ = *(const s16x8*)(bp0 + ks*64);                                 \
      s16x8 b1_ = *(const s16x8*)(bp1 + ks*64);                                 \
      s16x8 b2_ = *(const s16x8*)(bp2 + ks*64);                                 \
      s16x8 b3_ = *(const s16x8*)(bp3 + ks*64);                                 \
      __builtin_amdgcn_s_setprio(1);                                            \
      acc[0][0] = __builtin_amdgcn_mfma_f32_16x16x32_bf16(af0_, b0_, acc[0][0], 0, 0, 0); \
      acc[1][0] = __builtin_amdgcn_mfma_f32_16x16x32_bf16(af1_, b0_, acc[1][0], 0, 0, 0); \
      acc[2][0] = __builtin_amdgcn_mfma_f32_16x16x32_bf16(af2_, b0_, acc[2][0], 0, 0, 0); \
      acc[3][0] = __builtin_amdgcn_mfma_f32_16x16x32_bf16(af3_, b0_, acc[3][0], 0, 0, 0); \
      acc[0][1] = __builtin_amdgcn_mfma_f32_16x16x32_bf16(af0_, b1_, acc[0][1], 0, 0, 0); \
      acc[1][1] = __builtin_amdgcn_mfma_f32_16x16x32_bf16(af1_, b1_, acc[1][1], 0, 0, 0); \
      acc[2][1] = __builtin_amdgcn_mfma_f32_16x16x32_bf16(af2_, b1_, acc[2][1], 0, 0, 0); \
      acc[3][1] = __builtin_amdgcn_mfma_f32_16x16x32_bf16(af3_, b1_, acc[3][1], 0, 0, 0); \
      acc[0][2] = __builtin_amdgcn_mfma_f32_16x16x32_bf16(af0_, b2_, acc[0][2], 0, 0, 0); \
      acc[1][2] = __builtin_amdgcn_mfma_f32_16x16x32_bf16(af1_, b2_, acc[1][2], 0, 0, 0); \
      acc[2][2] = __builtin_amdgcn_mfma_f32_16x16x32_bf16(af2_, b2_, acc[2][2], 0, 0, 0); \
      acc[3][2] = __builtin_amdgcn_mfma_f32_16x16x32_bf16(af3_, b2_, acc[3][2], 0, 0, 0); \
      acc[0][3] = __builtin_amdgcn_mfma_f32_16x16x32_bf16(af0_, b3_, acc[0][3], 0, 0, 0); \
      acc[1][3] = __builtin_amdgcn_mfma_f32_16x16x32_bf16(af1_, b3_, acc[1][3], 0, 0, 0); \
      acc[2][3] = __builtin_amdgcn_mfma_f32_16x16x32_bf16(af2_, b3_, acc[2][3], 0, 0, 0); \
      acc[3][3] = __builtin_amdgcn_mfma_f32_16x16x32_bf16(af3_, b3_, acc[3][3], 0, 0, 0); \
      __builtin_amdgcn_s_setprio(0);                                            \
    }                                                                           \
  } while (0)

  // recombine: acc[2*pr][nt] = ch0-3 of point (pr*4+g), acc[2*pr+1][nt] = ch4-7
#define RC_T(BASE) do {                                                         \
    _Pragma("unroll")                                                           \
    for (int pr = 0; pr < 2; ++pr){                                             \
      _Pragma("unroll")                                                         \
      for (int nt = 0; nt < 4; ++nt){                                           \
        f32x4 v_ = acc[2*pr][nt];                                               \
        f32x4 w_ = acc[2*pr+1][nt];                                             \
        float gv_ = fast_tanh(v_[0] + b2c[nt]);                                 \
        float s2_ = 1.f - gv_*gv_;                                              \
        float t2_ = -2.f * gv_ * s2_;                                           \
        float r0_ = gv_,       r1_ = s2_*v_[1], r2_ = s2_*v_[2], r3_ = s2_*v_[3]; \
        float r4_ = s2_*w_[0];                                                  \
        float r5_ = fmaf(t2_*v_[1], v_[1], s2_*w_[1]);                          \
        float r6_ = fmaf(t2_*v_[2], v_[2], s2_*w_[2]);                          \
        float r7_ = fmaf(t2_*v_[3], v_[3], s2_*w_[3]);                          \
        int colb_ = (q*64 + nt*16 + r16) << 1;                                  \
        int rb_   = pr*16384 + (g*4)*512;                                       \
        unsigned u_;                                                            \
        u_ = cvtpk_bf16(r0_, r4_);                                              \
        *(unsigned short*)((BASE) + rb_        + (colb_ ^ ((((g&1)<<2)+0) << 4)))        = (unsigned short)u_; \
        *(unsigned short*)((BASE) + rb_        + (colb_ ^ ((((g&1)<<2)+0) << 4)) + 8192) = (unsigned short)(u_ >> 16); \
        u_ = cvtpk_bf16(r1_, r5_);                                              \
        *(unsigned short*)((BASE) + rb_ + 512  + (colb_ ^ ((((g&1)<<2)+1) << 4)))        = (unsigned short)u_; \
        *(unsigned short*)((BASE) + rb_ + 512  + (colb_ ^ ((((g&1)<<2)+1) << 4)) + 8192) = (unsigned short)(u_ >> 16); \
        u_ = cvtpk_bf16(r2_, r6_);                                              \
        *(unsigned short*)((BASE) + rb_ + 1024 + (colb_ ^ ((((g&1)<<2)+2) << 4)))        = (unsigned short)u_; \
        *(unsigned short*)((BASE) + rb_ + 1024 + (colb_ ^ ((((g&1)<<2)+2) << 4)) + 8192) = (unsigned short)(u_ >> 16); \
        u_ = cvtpk_bf16(r3_, r7_);                                              \
        *(unsigned short*)((BASE) + rb_ + 1536 + (colb_ ^ ((((g&1)<<2)+3) << 4)))        = (unsigned short)u_; \
        *(unsigned short*)((BASE) + rb_ + 1536 + (colb_ ^ ((((g&1)<<2)+3) << 4)) + 8192) = (unsigned short)(u_ >> 16); \
      }                                                                         \
    }                                                                           \
  } while (0)

  // GEMM3 + in-register residual tail (verified in R6)
#define G3_T(BASE, NBASE) do {                                                  \
    f32x4 a3_ = (f32x4){0.f, 0.f, 0.f, 0.f};                                    \
    _Pragma("unroll")                                                           \
    for (int ks = 0; ks < 8; ++ks){                                             \
      int X_ = ((ks*64) + (g << 4)) ^ g3sw;                                     \
      s16x8 av_ = *(const s16x8*)((BASE) + g3off + X_);                         \
      s16x8 bv_ = *(const s16x8*)(w3tB + ks*64);                                \
      a3_ = __builtin_amdgcn_mfma_f32_16x16x32_bf16(av_, bv_, a3_, 0, 0, 0);    \
    }                                                                           \
    float o4_ = __shfl_xor(a3_[0], 32, 64);                                     \
    float o5_ = __shfl_xor(a3_[1], 32, 64);                                     \
    float o6_ = __shfl_xor(a3_[2], 32, 64);                                     \
    float o7_ = __shfl_xor(a3_[3], 32, 64);                                     \
    float o0_ = a3_[0] + b3v, o1_ = a3_[1], o2_ = a3_[2], o3_ = a3_[3];         \
    int sl_ = lane & 16;                                                        \
    float u0_ = __shfl(o0_, sl_ | 0, 64);                                       \
    float u1_ = __shfl(o0_, sl_ | 1, 64);                                       \
    float u2_ = __shfl(o0_, sl_ | 2, 64);                                       \
    float rhoA_ = __shfl(o0_, sl_ | 4, 64);                                     \
    float gpx_ = __shfl(o1_, sl_ | 3, 64);                                      \
    float gpy_ = __shfl(o2_, sl_ | 3, 64);                                      \
    float gpz_ = __shfl(o3_, sl_ | 3, 64);                                      \
    float c00_ = __shfl(o1_, sl_ | 0, 64);                                      \
    float c11_ = __shfl(o2_, sl_ | 1, 64);                                      \
    float c22_ = __shfl(o3_, sl_ | 2, 64);                                      \
    float rho_ = 1000.f * (1.f + 0.1f * fast_tanh(rhoA_));                      \
    float rr_  = __builtin_amdgcn_rcpf(rho_);                                   \
    float vis_ = visc[(NBASE) + ptL];                                           \
    float lap_ = o5_ + o6_ + o7_;                                               \
    float cv_  = u0_*o1_ + u1_*o2_ + u2_*o3_;                                   \
    float gp_  = (r16 == 0) ? gpx_ : ((r16 == 1) ? gpy_ : gpz_);                \
    float R_   = o4_ + cv_ + gp_*rr_ - vis_*lap_ + ((r16 == 1) ? 9.81f : 0.f);  \
    if (lane < 32){                                                             \
      if (r16 < 3) accM += R_*R_;                                               \
      else if (r16 == 3){ float Rc_ = c00_ + c11_ + c22_; accC += Rc_*Rc_; }    \
    }                                                                           \
  } while (0)

  // ---------------- anti-phased interval loop ----------------
  // Group action index a = k - grp:
  //   a == 0           : L1(tile grp) -> buf[grp][0]
  //   a == 2j+1 (M)    : GEMM3(j-1) from buf[(j-1)&1]; GEMM2(j) from buf[j&1]
  //   a == 2j+2 (V)    : RC(j) -> buf[j&1]; L1(j+1) -> buf[(j+1)&1]
  #pragma unroll 1
  for (int k = 0; k <= 34; ++k){
    int a = k - grp;
    if (a == 0){
      L1_T(tbase + grp*TPB, sA + (grp << 1)*TSZ);
    } else if (a > 0 && a <= 33){
      if (a & 1){
        int j = (a - 1) >> 1;
        if (j > 0)  G3_T(sA + ((grp << 1) | ((j-1) & 1))*TSZ, tbase + (2*(j-1)+grp)*TPB);
        if (j < 16) G2_T(sA + ((grp << 1) | (j & 1))*TSZ);
      } else {
        int j = (a - 2) >> 1;
        RC_T(sA + ((grp << 1) | (j & 1))*TSZ);
        if (j < 15) L1_T(tbase + (2*(j+1)+grp)*TPB, sA + ((grp << 1) | ((j+1) & 1))*TSZ);
      }
    }
    __syncthreads();
  }

  // ---------------- block reduction (deterministic) ----------------
  #pragma unroll
  for (int off = 1; off < 64; off <<= 1){
    accM += __shfl_xor(accM, off, 64);
    accC += __shfl_xor(accC, off, 64);
  }
  float* red = (float*)sA;
  if (lane == 0){ red[wid*2] = accM; red[wid*2+1] = accC; }
  __syncthreads();
  if (t == 0){
    float m = 0.f, c = 0.f;
    #pragma unroll
    for (int w = 0; w < 8; ++w){ m += red[w*2]; c += red[w*2+1]; }
    float2 pr; pr.x = m; pr.y = c;
    *(float2*)(parts + blk*2) = pr;
  }
#undef L1_T
#undef G2_T
#undef RC_T
#undef G3_T
}

__global__ void ns_reduce(const float* __restrict__ parts, float* __restrict__ out){
  int t = threadIdx.x;
  float a = 0.f, b = 0.f;
  if (t < NBLOCKS){ a = parts[2*t]; b = parts[2*t + 1]; }
  #pragma unroll
  for (int off = 32; off; off >>= 1){
    a += __shfl_down(a, off, 64);
    b += __shfl_down(b, off, 64);
  }
  __shared__ float sa[4], sb[4];
  int wid = t >> 6, lane = t & 63;
  if (lane == 0){ sa[wid] = a; sb[wid] = b; }
  __syncthreads();
  if (t == 0){
    float A = sa[0] + sa[1] + sa[2] + sa[3];
    float B = sb[0] + sb[1] + sb[2] + sb[3];
    float mom  = A / (float)NPTS;
    float cont = B / (float)NPTS;
    out[0] = mom + 10.f * cont;
    out[1] = mom;
    out[2] = cont;
  }
}

extern "C" void kernel_launch(void* const* d_in, const int* in_sizes, int n_in,
                              void* d_out, int out_size, void* d_ws, size_t ws_size,
                              hipStream_t stream) {
  const float* pts   = (const float*)d_in[0];
  const float* times = (const float*)d_in[1];
  const float* visc  = (const float*)d_in[2];
  const float* W1    = (const float*)d_in[3];
  const float* b1    = (const float*)d_in[4];
  const float* W2    = (const float*)d_in[5];
  const float* b2    = (const float*)d_in[6];
  const float* W3    = (const float*)d_in[7];
  const float* b3    = (const float*)d_in[8];
  float* out = (float*)d_out;

  unsigned short* w2t = (unsigned short*)d_ws;
  unsigned short* w3t = (unsigned short*)((char*)d_ws + W3T_OFF);
  float* parts        = (float*)((char*)d_ws + PART_OFF);

  prep_w2t<<<256, 256, 0, stream>>>(W2, w2t);
  prep_w3t<<<16, 256, 0, stream>>>(W3, w3t);
  ns_main<<<NBLOCKS, 512, 0, stream>>>(pts, times, visc, W1, b1, b2, b3, w2t, w3t, parts);
  ns_reduce<<<1, 256, 0, stream>>>(parts, out);
}